// Round 5
// baseline (621.958 us; speedup 1.0000x reference)
//
#include <hip/hip_runtime.h>
#include <stdint.h>

#define SLEN 2048
#define BSZ  2
#define HSZ  1024
#define FFND 4096
#define NEXP 8
#define TOPK 2
#define NTOK (SLEN*BSZ)        // 4096
#define NSLOT (NTOK*TOPK)      // 8192

// ---- 8-phase 256x256 GEMM geometry ----
#define BM2 256
#define BN2 256
#define BK2 64                 // K-tile; two 32-k halves
#define KSPLIT 2               // gemm2: N=1024 -> only 4 n-blocks; split K for grid
#define HALFK (FFND / KSPLIT)  // 2048

using short8 = __attribute__((ext_vector_type(8))) short;
using f32x4  = __attribute__((ext_vector_type(4))) float;

typedef __attribute__((address_space(1))) const unsigned int gu32;
typedef __attribute__((address_space(3))) unsigned int lu32;

__device__ inline void async_copy16(const void* g, void* l){
  // DMA 16B/lane global->LDS; LDS dest = wave-uniform base + lane*16
  __builtin_amdgcn_global_load_lds((gu32*)g, (lu32*)l, 16, 0, 0);
}

__device__ inline unsigned short f2bf(float f){
  unsigned u = __builtin_bit_cast(unsigned, f);
  u += 0x7FFFu + ((u >> 16) & 1u);      // round-to-nearest-even
  return (unsigned short)(u >> 16);
}

__device__ inline float gelu_tanh(float x){
  // jax.nn.gelu default (approximate=True)
  float u = 0.7978845608028654f * (x + 0.044715f * x * x * x);
  return 0.5f * x * (1.0f + tanhf(u));
}

// ---------------- fused routing: count + scan + assign (one block) ----------
__global__ __launch_bounds__(1024) void k_route(const int* __restrict__ ei,
                                                const float* __restrict__ ew,
                                                int* __restrict__ counts,
                                                int* __restrict__ offsets,
                                                int* __restrict__ rowT,
                                                float* __restrict__ rowC){
  __shared__ int hist[NEXP];
  __shared__ int fill[NEXP];
  const int tid = threadIdx.x;
  if (tid < NEXP) hist[tid] = 0;
  __syncthreads();
  int myE[NSLOT / 1024];
  #pragma unroll
  for (int p = 0; p < NSLOT / 1024; p++){
    myE[p] = ei[tid + p * 1024];
    atomicAdd(&hist[myE[p]], 1);
  }
  __syncthreads();
  if (tid == 0){
    int acc = 0;
    for (int e = 0; e < NEXP; e++){
      offsets[e] = acc; counts[e] = hist[e]; fill[e] = acc; acc += hist[e];
    }
  }
  __syncthreads();
  #pragma unroll
  for (int p = 0; p < NSLOT / 1024; p++){
    int i = tid + p * 1024;
    int slot = atomicAdd(&fill[myE[p]], 1);
    rowT[slot] = i >> 1;       // token index (i = t*TOPK + k)
    rowC[slot] = ew[i];
  }
}

__global__ void k_gather(const float* __restrict__ x, const int* __restrict__ rowT,
                         unsigned short* __restrict__ Xg){
  int slot = blockIdx.x;
  int t = rowT[slot];
  int c = threadIdx.x * 4;
  float4 v = *(const float4*)(x + (size_t)t * HSZ + c);
  ushort4 o;
  o.x = f2bf(v.x); o.y = f2bf(v.y); o.z = f2bf(v.z); o.w = f2bf(v.w);
  *(ushort4*)(Xg + (size_t)slot * HSZ + c) = o;
}

// ------- merged weight transform: fp32 [R][C] -> bf16 [C][R], w1 & w2 -------
__global__ __launch_bounds__(256) void k_transpose2(const float* __restrict__ w1,
                                                    const float* __restrict__ w2,
                                                    unsigned short* __restrict__ Wt1,
                                                    unsigned short* __restrict__ Wt2){
  __shared__ unsigned short tile[64][65];
  const int tid = threadIdx.x;
  int z = blockIdx.y;
  const float* src; unsigned short* dst; int R, C, r0, c0;
  if (z < NEXP){
    src = w1 + (size_t)z * HSZ * FFND; dst = Wt1 + (size_t)z * HSZ * FFND;
    R = HSZ; C = FFND;
    c0 = (blockIdx.x & 63) * 64; r0 = (blockIdx.x >> 6) * 64;
  } else {
    z -= NEXP;
    src = w2 + (size_t)z * FFND * HSZ; dst = Wt2 + (size_t)z * FFND * HSZ;
    R = FFND; C = HSZ;
    c0 = (blockIdx.x & 15) * 64; r0 = (blockIdx.x >> 4) * 64;
  }
  #pragma unroll
  for (int p = 0; p < 4; p++){
    int r  = p * 16 + (tid >> 4);
    int cc = (tid & 15) * 4;
    float4 v = *(const float4*)(src + (size_t)(r0 + r) * C + c0 + cc);
    tile[r][cc]   = f2bf(v.x);
    tile[r][cc+1] = f2bf(v.y);
    tile[r][cc+2] = f2bf(v.z);
    tile[r][cc+3] = f2bf(v.w);
  }
  __syncthreads();
  #pragma unroll
  for (int p = 0; p < 4; p++){
    int c  = p * 16 + (tid >> 4);
    int rr = (tid & 15) * 4;
    ushort4 o;
    o.x = tile[rr][c]; o.y = tile[rr+1][c]; o.z = tile[rr+2][c]; o.w = tile[rr+3][c];
    *(ushort4*)(dst + (size_t)(c0 + c) * R + r0 + rr) = o;
  }
}

// ============ 8-phase 256x256 GEMM core (T2+T3+T4+T5, plain HIP) ============
// A: bf16 [rows x K] k-contig (lda elems), rows<=256 (tail clamped on stage,
// masked in epilogue). B: bf16 [256 x K] k-contig (pre-offset to n0, ldb).
// LDS: per operand a ring of 4 k-half slabs [256 rows][32 k] (16KB each);
//   slab for (tile t, khalf ks) = (2t+ks)&3. A at byte 0, B at byte 65536.
// Swizzle (T2, both-sides-or-neither): 16B k-slot s of row r lives at
//   LDS slot s^(r&3); stage reads global chunk (s^(r&3)), ds_read XORs too.
//   Cuts the 16-lane same-bank column read from 8/16-way to ~4-way.
// Schedule: 4 phases per K-tile = (ks,ihalf) in (0,0)(0,1)(1,0)(1,1).
//   Phase: [vmcnt(4) if ihalf==0] -> s_barrier -> ds_read (4 A + 4 B if
//   ihalf==0 else 4 A) -> stage ONE half of tile t+1 (2 gload_lds) ->
//   setprio(1) 16 MFMA setprio(0).
//   Stage order: p0:A.k0(t+1) p1:B.k0 p2:A.k1 p3:B.k1 => at each vmcnt(4)
//   exactly the 2 newest halves (4 loads/wave) may stay in flight; the 4
//   oldest (the halves the next reads need) are forced complete. Counted,
//   never 0 in the loop (T4).
__device__ __forceinline__ void gemm_core256(
    const unsigned short* __restrict__ Ag, int lda, int rows,
    const unsigned short* __restrict__ Bg, int ldb, int K,
    unsigned short* smem, f32x4 acc[8][4])
{
  const int tid  = threadIdx.x;
  const int lane = tid & 63;
  const int wid  = tid >> 6;
  const int wr   = wid >> 2;        // A row half owned by wave (0..1)
  const int wc   = wid & 3;         // B col quarter (0..3)
  const int q    = lane >> 4;
  const int l16  = lane & 15;

  char* smemc = (char*)smem;

  // ---- staging descriptors: 1024 chunks (16B) per half; this wave's two
  // chunks are c=wid*64+lane (rows 0..127) and c+512 (rows 128..255).
  const int srow = wid * 16 + (lane >> 2);       // 0..127
  const int sx   = (lane & 3) ^ (srow & 3);      // inverse-swizzled source slot
  const char* A8 = (const char*)Ag;
  const char* B8 = (const char*)Bg;
  unsigned ao0 = (unsigned)(min(srow,       rows - 1) * lda) * 2u + (unsigned)(sx << 4);
  unsigned ao1 = (unsigned)(min(srow + 128, rows - 1) * lda) * 2u + (unsigned)(sx << 4);
  unsigned bo0 = (unsigned)( srow        * ldb) * 2u + (unsigned)(sx << 4);
  unsigned bo1 = (unsigned)((srow + 128) * ldb) * 2u + (unsigned)(sx << 4);
  char* ldsA = smemc + wid * 1024;               // + slab*16384 (+8192 chunk1)
  char* ldsB = smemc + 65536 + wid * 1024;

  // ---- ds_read bases within a slab (row*64 + swizzled 16B slot) ----
  const int rxs = ((q ^ (lane & 3)) << 4);
  const unsigned rbA = (unsigned)((wr * 128 + l16) * 64 + rxs);
  const unsigned rbB = (unsigned)((wc * 64  + l16) * 64 + rxs);

  short8 bf[4];

  // prologue: stage tile 0 (k0 -> slab0, k1 -> slab1); 8 loads/wave in flight
  async_copy16(A8 + ao0,      ldsA);
  async_copy16(A8 + ao1,      ldsA + 8192);
  async_copy16(B8 + bo0,      ldsB);
  async_copy16(B8 + bo1,      ldsB + 8192);
  async_copy16(A8 + ao0 + 64, ldsA + 16384);
  async_copy16(A8 + ao1 + 64, ldsA + 16384 + 8192);
  async_copy16(B8 + bo0 + 64, ldsB + 16384);
  async_copy16(B8 + bo1 + 64, ldsB + 16384 + 8192);
  ao0 += 128; ao1 += 128; bo0 += 128; bo1 += 128;   // -> tile 1

  const int T = K / BK2;   // even (K=1024/2048)

  auto phase = [&](int ks, int ih, int sRd, int sW, int stA){
    if (ih == 0) asm volatile("s_waitcnt vmcnt(4)" ::: "memory");
    __builtin_amdgcn_s_barrier();
    asm volatile("" ::: "memory");
    const char* aslab = smemc + sRd * 16384;
    const char* bslab = smemc + 65536 + sRd * 16384;
    if (ih == 0){
      #pragma unroll
      for (int j = 0; j < 4; j++)
        bf[j] = *(const short8*)(bslab + rbB + j * 1024);
    }
    short8 af[4];
    #pragma unroll
    for (int ii = 0; ii < 4; ii++)
      af[ii] = *(const short8*)(aslab + rbA + (ih * 4 + ii) * 1024);
    const unsigned kb = (unsigned)(ks << 6);    // staged half's k-byte offset
    if (stA){
      async_copy16(A8 + (ao0 + kb), ldsA + sW * 16384);
      async_copy16(A8 + (ao1 + kb), ldsA + sW * 16384 + 8192);
    } else {
      async_copy16(B8 + (bo0 + kb), ldsB + sW * 16384);
      async_copy16(B8 + (bo1 + kb), ldsB + sW * 16384 + 8192);
    }
    __builtin_amdgcn_s_setprio(1);
    #pragma unroll
    for (int ii = 0; ii < 4; ii++)
      #pragma unroll
      for (int j = 0; j < 4; j++)
        acc[ih*4+ii][j] = __builtin_amdgcn_mfma_f32_16x16x32_bf16(af[ii], bf[j], acc[ih*4+ii][j], 0, 0, 0);
    __builtin_amdgcn_s_setprio(0);
  };

  for (int t = 0; t < T; t += 2){
    // tile t (even): read slabs {0,1}; stage tile t+1 -> slabs {2,3}
    phase(0, 0, 0, 2, 1);
    phase(0, 1, 0, 2, 0);
    phase(1, 0, 1, 3, 1);
    phase(1, 1, 1, 3, 0);
    if (t + 3 <= T){ ao0 += 128; ao1 += 128; bo0 += 128; bo1 += 128; }
    // tile t+1 (odd): read {2,3}; stage tile t+2 -> {0,1}
    phase(0, 0, 2, 0, 1);
    phase(0, 1, 2, 0, 0);
    phase(1, 0, 3, 1, 1);
    phase(1, 1, 3, 1, 0);
    if (t + 4 <= T){ ao0 += 128; ao1 += 128; bo0 += 128; bo1 += 128; }
  }
  // drain stale prefetches before LDS reuse / exit
  asm volatile("s_waitcnt vmcnt(0)" ::: "memory");
  __builtin_amdgcn_s_barrier();
  asm volatile("" ::: "memory");
}

// ---------------- GEMM1: H = gelu(Xg @ Wt1[e]^T), 256x256 tile --------------
__global__ __launch_bounds__(512, 2) void k_gemm1(const unsigned short* __restrict__ Xg,
                                                  const unsigned short* __restrict__ Wt1,
                                                  unsigned short* __restrict__ H,
                                                  const int* __restrict__ counts,
                                                  const int* __restrict__ offsets)
{
  __shared__ unsigned short smem[65536];       // 128 KB ring (A 64K | B 64K)
  const int e    = blockIdx.z;
  const int cnt  = counts[e];
  const int mblk = blockIdx.y;
  if (mblk * BM2 >= cnt) return;
  const int n0   = blockIdx.x * BN2;
  const int row0 = offsets[e] + mblk * BM2;
  const int rows = min(BM2, cnt - mblk * BM2);

  f32x4 acc[8][4] = {};
  gemm_core256(Xg + (size_t)row0 * HSZ, HSZ, rows,
               Wt1 + (size_t)e * HSZ * FFND + (size_t)n0 * HSZ, HSZ, HSZ,
               smem, acc);

  const int lane = threadIdx.x & 63, wid = threadIdx.x >> 6;
  const int wr = wid >> 2, wc = wid & 3;
  const int q = lane >> 4, l16 = lane & 15;

  // per-wave LDS repack (wave-private scratch; core already barriered):
  // 16x64 bf16 subtile (stride 68), b128 readback, dwordx4 global stores.
  unsigned short* scr = smem + wid * (16 * 68);
  #pragma unroll
  for (int i = 0; i < 8; i++){
    #pragma unroll
    for (int j = 0; j < 4; j++)
      #pragma unroll
      for (int r = 0; r < 4; r++)
        scr[(q * 4 + r) * 68 + j * 16 + l16] = f2bf(gelu_tanh(acc[i][j][r]));
    #pragma unroll
    for (int p = 0; p < 2; p++){
      int rr = p * 8 + (lane >> 3);
      int cc = (lane & 7) * 8;
      short8 v = *(const short8*)(scr + rr * 68 + cc);
      int grow = wr * 128 + i * 16 + rr;
      if (grow < rows)
        *(short8*)(H + (size_t)(row0 + grow) * FFND + n0 + wc * 64 + cc) = v;
    }
  }
}

// ------- GEMM2: out[t] += coef * (H @ Wt2[e]^T), 256x256 tile, K-split ------
__global__ __launch_bounds__(512, 2) void k_gemm2(const unsigned short* __restrict__ H,
                                                  const unsigned short* __restrict__ Wt2,
                                                  float* __restrict__ out,
                                                  const int* __restrict__ counts,
                                                  const int* __restrict__ offsets,
                                                  const int* __restrict__ rowT,
                                                  const float* __restrict__ rowC)
{
  __shared__ unsigned short smem[65536];       // 128 KB
  const int e    = blockIdx.z;
  const int cnt  = counts[e];
  const int ks2  = blockIdx.y & 1;             // K-half owned by this block
  const int mblk = blockIdx.y >> 1;
  if (mblk * BM2 >= cnt) return;
  const int n0   = blockIdx.x * BN2;
  const int row0 = offsets[e] + mblk * BM2;
  const int rows = min(BM2, cnt - mblk * BM2);

  f32x4 acc[8][4] = {};
  gemm_core256(H + (size_t)row0 * FFND + ks2 * HALFK, FFND, rows,
               Wt2 + (size_t)e * FFND * HSZ + (size_t)n0 * FFND + ks2 * HALFK, FFND,
               HALFK, smem, acc);

  const int lane = threadIdx.x & 63, wid = threadIdx.x >> 6;
  const int wr = wid >> 2, wc = wid & 3;
  const int q = lane >> 4, l16 = lane & 15;
  #pragma unroll
  for (int i = 0; i < 8; i++)
    #pragma unroll
    for (int r = 0; r < 4; r++){
      int row = wr * 128 + i * 16 + q * 4 + r;
      if (row < rows){
        int g = row0 + row;
        float cf = rowC[g];
        float* op = out + (size_t)rowT[g] * HSZ + n0 + wc * 64;
        #pragma unroll
        for (int j = 0; j < 4; j++)
          atomicAdd(op + j * 16 + l16, cf * acc[i][j][r]);
      }
    }
}

// ---------------- launch ----------------
static inline size_t align_up(size_t v, size_t a){ return (v + a - 1) & ~(a - 1); }

extern "C" void kernel_launch(void* const* d_in, const int* in_sizes, int n_in,
                              void* d_out, int out_size, void* d_ws, size_t ws_size,
                              hipStream_t stream) {
  const float* x  = (const float*)d_in[0];
  const float* ew = (const float*)d_in[1];
  const int*   ei = (const int*)d_in[2];
  const float* w1 = (const float*)d_in[3];
  const float* w2 = (const float*)d_in[4];
  float* out = (float*)d_out;

  // workspace layout (bytes)
  char* base = (char*)d_ws;
  size_t off = 0;
  int* counts  = (int*)(base + off); off += 64;
  int* offsets = (int*)(base + off); off = align_up(off + 64, 4096);
  int* rowT    = (int*)(base + off); off += (size_t)NSLOT * 4;
  float* rowC  = (float*)(base + off); off = align_up(off + (size_t)NSLOT * 4, 1 << 20);
  unsigned short* Xg  = (unsigned short*)(base + off); off = align_up(off + (size_t)NSLOT * HSZ * 2, 1 << 20);
  unsigned short* H   = (unsigned short*)(base + off); off = align_up(off + (size_t)NSLOT * FFND * 2, 1 << 20);
  unsigned short* Wt1 = (unsigned short*)(base + off); off = align_up(off + (size_t)NEXP * HSZ * FFND * 2, 1 << 20);
  unsigned short* Wt2 = (unsigned short*)(base + off); off += (size_t)NEXP * FFND * HSZ * 2;
  (void)ws_size;

  hipMemsetAsync(d_out, 0, (size_t)out_size * sizeof(float), stream);

  k_route <<<1, 1024, 0, stream>>>(ei, ew, counts, offsets, rowT, rowC);
  k_gather<<<NSLOT, 256, 0, stream>>>(x, rowT, Xg);

  // merged weight transform: z<8 -> w1 [HSZ][FFND]->Wt1; z>=8 -> w2 -> Wt2
  k_transpose2<<<dim3(1024, 2 * NEXP), 256, 0, stream>>>(w1, w2, Wt1, Wt2);

  // worst case one expert owns all 8192 rows -> 32 m-blocks; extras early-exit
  k_gemm1<<<dim3(FFND / BN2, 32, NEXP), 512, 0, stream>>>(Xg, Wt1, H, counts, offsets);
  k_gemm2<<<dim3(HSZ / BN2, 32 * KSPLIT, NEXP), 512, 0, stream>>>(H, Wt2, out, counts, offsets, rowT, rowC);
}

// Round 7
// 577.068 us; speedup vs baseline: 1.0778x; 1.0778x over previous
//
#include <hip/hip_runtime.h>
#include <stdint.h>

#define SLEN 2048
#define BSZ  2
#define HSZ  1024
#define FFND 4096
#define NEXP 8
#define TOPK 2
#define NTOK (SLEN*BSZ)        // 4096
#define NSLOT (NTOK*TOPK)      // 8192

#define BM 128
#define BN 128
#define BK 32
#define STAGE (BM * BK)        // 4096 shorts per operand per stage
#define RING 3                 // LDS ring depth: prefetch distance 2 K-tiles

// K-split for gemm2: N=1024 gives only 8 n-blocks; KSPLIT=2 -> 1024 working
// blocks so the 3-blocks/CU residency (48KB LDS) is actually fillable.
#define KSPLIT 2
#define HALFK (FFND / KSPLIT)  // 2048

using short8 = __attribute__((ext_vector_type(8))) short;
using f32x4  = __attribute__((ext_vector_type(4))) float;

typedef __attribute__((address_space(1))) const unsigned int gu32;
typedef __attribute__((address_space(3))) unsigned int lu32;

__device__ inline void async_copy16(const void* g, void* l){
  // DMA 16B/lane global->LDS; LDS dest = wave-uniform base + lane*16
  __builtin_amdgcn_global_load_lds((gu32*)g, (lu32*)l, 16, 0, 0);
}

__device__ inline unsigned short f2bf(float f){
  unsigned u = __builtin_bit_cast(unsigned, f);
  u += 0x7FFFu + ((u >> 16) & 1u);      // round-to-nearest-even
  return (unsigned short)(u >> 16);
}

__device__ inline float gelu_tanh(float x){
  // jax.nn.gelu default (approximate=True)
  float u = 0.7978845608028654f * (x + 0.044715f * x * x * x);
  return 0.5f * x * (1.0f + tanhf(u));
}

// ---------------- fused routing: count + scan + assign (one block) ----------
__global__ __launch_bounds__(1024) void k_route(const int* __restrict__ ei,
                                                const float* __restrict__ ew,
                                                int* __restrict__ counts,
                                                int* __restrict__ offsets,
                                                int* __restrict__ rowT,
                                                float* __restrict__ rowC){
  __shared__ int hist[NEXP];
  __shared__ int fill[NEXP];
  const int tid = threadIdx.x;
  if (tid < NEXP) hist[tid] = 0;
  __syncthreads();
  int myE[NSLOT / 1024];
  #pragma unroll
  for (int p = 0; p < NSLOT / 1024; p++){
    myE[p] = ei[tid + p * 1024];
    atomicAdd(&hist[myE[p]], 1);
  }
  __syncthreads();
  if (tid == 0){
    int acc = 0;
    for (int e = 0; e < NEXP; e++){
      offsets[e] = acc; counts[e] = hist[e]; fill[e] = acc; acc += hist[e];
    }
  }
  __syncthreads();
  #pragma unroll
  for (int p = 0; p < NSLOT / 1024; p++){
    int i = tid + p * 1024;
    int slot = atomicAdd(&fill[myE[p]], 1);
    rowT[slot] = i >> 1;       // token index (i = t*TOPK + k)
    rowC[slot] = ew[i];
  }
}

__global__ void k_gather(const float* __restrict__ x, const int* __restrict__ rowT,
                         unsigned short* __restrict__ Xg){
  int slot = blockIdx.x;
  int t = rowT[slot];
  int c = threadIdx.x * 4;
  float4 v = *(const float4*)(x + (size_t)t * HSZ + c);
  ushort4 o;
  o.x = f2bf(v.x); o.y = f2bf(v.y); o.z = f2bf(v.z); o.w = f2bf(v.w);
  *(ushort4*)(Xg + (size_t)slot * HSZ + c) = o;
}

// ------- merged weight transform: fp32 [R][C] -> bf16 [C][R], w1 & w2 -------
__global__ __launch_bounds__(256) void k_transpose2(const float* __restrict__ w1,
                                                    const float* __restrict__ w2,
                                                    unsigned short* __restrict__ Wt1,
                                                    unsigned short* __restrict__ Wt2){
  __shared__ unsigned short tile[64][65];
  const int tid = threadIdx.x;
  int z = blockIdx.y;
  const float* src; unsigned short* dst; int R, C, r0, c0;
  if (z < NEXP){
    src = w1 + (size_t)z * HSZ * FFND; dst = Wt1 + (size_t)z * HSZ * FFND;
    R = HSZ; C = FFND;
    c0 = (blockIdx.x & 63) * 64; r0 = (blockIdx.x >> 6) * 64;
  } else {
    z -= NEXP;
    src = w2 + (size_t)z * FFND * HSZ; dst = Wt2 + (size_t)z * FFND * HSZ;
    R = FFND; C = HSZ;
    c0 = (blockIdx.x & 15) * 64; r0 = (blockIdx.x >> 4) * 64;
  }
  #pragma unroll
  for (int p = 0; p < 4; p++){
    int r  = p * 16 + (tid >> 4);
    int cc = (tid & 15) * 4;
    float4 v = *(const float4*)(src + (size_t)(r0 + r) * C + c0 + cc);
    tile[r][cc]   = f2bf(v.x);
    tile[r][cc+1] = f2bf(v.y);
    tile[r][cc+2] = f2bf(v.z);
    tile[r][cc+3] = f2bf(v.w);
  }
  __syncthreads();
  #pragma unroll
  for (int p = 0; p < 4; p++){
    int c  = p * 16 + (tid >> 4);
    int rr = (tid & 15) * 4;
    ushort4 o;
    o.x = tile[rr][c]; o.y = tile[rr+1][c]; o.z = tile[rr+2][c]; o.w = tile[rr+3][c];
    *(ushort4*)(dst + (size_t)(c0 + c) * R + r0 + rr) = o;
  }
}

// -------- GEMM core: ring-3 LDS, distance-2 prefetch, counted vmcnt --------
// A: bf16 [rows x K] k-contiguous (lda elems). B: bf16 [128 x K] k-contiguous
// (pre-offset to row n0, ldb elems). LDS: As/Bs each RING stages x [128][32].
// Loop invariant at iter k: tiles k (needed now), k+1, k+2 staged; exactly
// 8 loads/wave outstanding -> vmcnt(4) completes tile k (4 oldest loads),
// leaves k+1/k+2 in flight. A tile is staged TWO iters (~600+ cyc) before
// use, covering L2/HBM latency that distance-1 prefetch (R1/R4/R5, all ~166us
// with all pipes idle) provably could not. vmcnt never drains to 0 in-loop.
// Tail: stage addresses clamp at tile niter-1 into dead ring slots (in-bounds
// re-reads) so the count ladder stays uniform.
__device__ inline void gemm_core(const unsigned short* __restrict__ Ag, int lda, int rows,
                                 const unsigned short* __restrict__ Bg, int ldb, int K,
                                 unsigned short* As, unsigned short* Bs,
                                 f32x4 acc[4][4])
{
  const int tid  = threadIdx.x;
  const int lane = tid & 63;
  const int wid  = tid >> 6;
  const int wm   = (wid & 1) * 64;
  const int wn   = (wid >> 1) * 64;
  const int q    = lane >> 4;
  const int l16  = lane & 15;

  // chunk ids (16B each) owned by this lane
  const int c0 = (wid * 2) * 64 + lane;
  const int c1 = c0 + 64;
  // per-lane 32-bit byte offsets over uniform bases (56 VGPR total, R4-proven)
  unsigned aoff0 = (unsigned)(min(c0 >> 2, rows - 1) * lda + (c0 & 3) * 8) * 2u;
  unsigned aoff1 = (unsigned)(min(c1 >> 2, rows - 1) * lda + (c1 & 3) * 8) * 2u;
  unsigned boff0 = (unsigned)((c0 >> 2) * ldb + (c0 & 3) * 8) * 2u;
  unsigned boff1 = (unsigned)((c1 >> 2) * ldb + (c1 & 3) * 8) * 2u;
  const char* A8 = (const char*)Ag;
  const char* B8 = (const char*)Bg;
  unsigned short* al0 = As + (wid * 2) * 512;
  unsigned short* bl0 = Bs + (wid * 2) * 512;

  auto stage = [&](int s){
    async_copy16(A8 + aoff0, al0 + s * STAGE);
    async_copy16(B8 + boff0, bl0 + s * STAGE);
    async_copy16(A8 + aoff1, al0 + s * STAGE + 512);
    async_copy16(B8 + boff1, bl0 + s * STAGE + 512);
  };
  auto advance = [&](){ aoff0 += BK * 2; aoff1 += BK * 2; boff0 += BK * 2; boff1 += BK * 2; };

  const int niter = K / BK;
  stage(0); advance();
  stage(1); advance();              // offsets now point at tile 2

  int rd = 0, wr2 = 2;              // ring slots: read tile k, write tile k+2
  for (int k = 0; k < niter; k++){
    // tile k guaranteed complete; k+1,k+2 may stay in flight (counted, T4)
    asm volatile("s_waitcnt vmcnt(4)" ::: "memory");
    __builtin_amdgcn_s_barrier();
    asm volatile("" ::: "memory");

    stage(wr2);                     // tile k+2 (or clamped dead re-read at tail)
    if (k + 3 < niter) advance();

    const unsigned short* Ak = As + rd * STAGE;
    const unsigned short* Bk = Bs + rd * STAGE;
    short8 af[4], bfr[4];
    #pragma unroll
    for (int i = 0; i < 4; i++)
      af[i] = *(const short8*)(Ak + (wm + i * 16 + l16) * BK + q * 8);
    #pragma unroll
    for (int j = 0; j < 4; j++)
      bfr[j] = *(const short8*)(Bk + (wn + j * 16 + l16) * BK + q * 8);

    __builtin_amdgcn_s_setprio(1);
    #pragma unroll
    for (int i = 0; i < 4; i++)
      #pragma unroll
      for (int j = 0; j < 4; j++)
        acc[i][j] = __builtin_amdgcn_mfma_f32_16x16x32_bf16(af[i], bfr[j], acc[i][j], 0, 0, 0);
    __builtin_amdgcn_s_setprio(0);

    rd  = (rd  + 1 == RING) ? 0 : rd  + 1;
    wr2 = (wr2 + 1 == RING) ? 0 : wr2 + 1;
  }
  // drain dead-slot prefetches before LDS reuse / exit
  asm volatile("s_waitcnt vmcnt(0)" ::: "memory");
  __builtin_amdgcn_s_barrier();
  asm volatile("" ::: "memory");
}

// ---------------- GEMM1: H = gelu(Xg @ Wt1[e]^T), 128x128 tile --------------
__global__ __launch_bounds__(256, 4) void k_gemm1(const unsigned short* __restrict__ Xg,
                                                  const unsigned short* __restrict__ Wt1,
                                                  unsigned short* __restrict__ H,
                                                  const int* __restrict__ counts,
                                                  const int* __restrict__ offsets)
{
  __shared__ unsigned short smem[2 * RING * STAGE];   // 48 KB -> 3 blocks/CU
  unsigned short* As = smem;
  unsigned short* Bs = smem + RING * STAGE;
  const int e    = blockIdx.z;
  const int cnt  = counts[e];
  const int mblk = blockIdx.y;
  if (mblk * BM >= cnt) return;
  const int n0   = blockIdx.x * BN;
  const int row0 = offsets[e] + mblk * BM;
  const int rows = min(BM, cnt - mblk * BM);

  f32x4 acc[4][4] = {};
  gemm_core(Xg + (size_t)row0 * HSZ, HSZ, rows,
            Wt1 + (size_t)e * HSZ * FFND + (size_t)n0 * HSZ, HSZ, HSZ, As, Bs, acc);
  __syncthreads();   // full drain before reusing smem as scratch

  const int lane = threadIdx.x & 63, wid = threadIdx.x >> 6;
  const int wm = (wid & 1) * 64, wn = (wid >> 1) * 64;
  const int q = lane >> 4, l16 = lane & 15;

  // per-wave LDS repack: 16x64 bf16 subtile (stride 68), b128 readback,
  // dwordx4 global stores. Scratch is wave-private.
  unsigned short* scr = smem + wid * (16 * 68);
  #pragma unroll
  for (int i = 0; i < 4; i++){
    #pragma unroll
    for (int j = 0; j < 4; j++)
      #pragma unroll
      for (int r = 0; r < 4; r++)
        scr[(q * 4 + r) * 68 + j * 16 + l16] = f2bf(gelu_tanh(acc[i][j][r]));
    #pragma unroll
    for (int p = 0; p < 2; p++){
      int rr = p * 8 + (lane >> 3);
      int cc = (lane & 7) * 8;
      short8 v = *(const short8*)(scr + rr * 68 + cc);
      int grow = wm + i * 16 + rr;
      if (grow < rows)
        *(short8*)(H + (size_t)(row0 + grow) * FFND + n0 + wn + cc) = v;
    }
  }
}

// ------- GEMM2: out[t] += coef * (H @ Wt2[e]^T), 128x128 tile, K-split ------
__global__ __launch_bounds__(256, 4) void k_gemm2(const unsigned short* __restrict__ H,
                                                  const unsigned short* __restrict__ Wt2,
                                                  float* __restrict__ out,
                                                  const int* __restrict__ counts,
                                                  const int* __restrict__ offsets,
                                                  const int* __restrict__ rowT,
                                                  const float* __restrict__ rowC)
{
  __shared__ unsigned short smem[2 * RING * STAGE];   // 48 KB
  unsigned short* As = smem;
  unsigned short* Bs = smem + RING * STAGE;
  const int e    = blockIdx.z;
  const int cnt  = counts[e];
  const int ks   = blockIdx.y % KSPLIT;        // K-half owned by this block
  const int mblk = blockIdx.y / KSPLIT;
  if (mblk * BM >= cnt) return;
  const int n0   = blockIdx.x * BN;
  const int row0 = offsets[e] + mblk * BM;
  const int rows = min(BM, cnt - mblk * BM);

  f32x4 acc[4][4] = {};
  gemm_core(H + (size_t)row0 * FFND + ks * HALFK, FFND, rows,
            Wt2 + (size_t)e * FFND * HSZ + (size_t)n0 * FFND + ks * HALFK, FFND,
            HALFK, As, Bs, acc);

  const int lane = threadIdx.x & 63, wid = threadIdx.x >> 6;
  const int wm = (wid & 1) * 64, wn = (wid >> 1) * 64;
  const int q = lane >> 4, l16 = lane & 15;
  #pragma unroll
  for (int i = 0; i < 4; i++)
    #pragma unroll
    for (int r = 0; r < 4; r++){
      int row = wm + i * 16 + q * 4 + r;
      if (row < rows){
        int g = row0 + row;
        float cf = rowC[g];
        float* op = out + (size_t)rowT[g] * HSZ + n0 + wn;
        #pragma unroll
        for (int j = 0; j < 4; j++)
          atomicAdd(op + j * 16 + l16, cf * acc[i][j][r]);
      }
    }
}

// ---------------- launch ----------------
static inline size_t align_up(size_t v, size_t a){ return (v + a - 1) & ~(a - 1); }

extern "C" void kernel_launch(void* const* d_in, const int* in_sizes, int n_in,
                              void* d_out, int out_size, void* d_ws, size_t ws_size,
                              hipStream_t stream) {
  const float* x  = (const float*)d_in[0];
  const float* ew = (const float*)d_in[1];
  const int*   ei = (const int*)d_in[2];
  const float* w1 = (const float*)d_in[3];
  const float* w2 = (const float*)d_in[4];
  float* out = (float*)d_out;

  // workspace layout (bytes)
  char* base = (char*)d_ws;
  size_t off = 0;
  int* counts  = (int*)(base + off); off += 64;
  int* offsets = (int*)(base + off); off = align_up(off + 64, 4096);
  int* rowT    = (int*)(base + off); off += (size_t)NSLOT * 4;
  float* rowC  = (float*)(base + off); off = align_up(off + (size_t)NSLOT * 4, 1 << 20);
  unsigned short* Xg  = (unsigned short*)(base + off); off = align_up(off + (size_t)NSLOT * HSZ * 2, 1 << 20);
  unsigned short* H   = (unsigned short*)(base + off); off = align_up(off + (size_t)NSLOT * FFND * 2, 1 << 20);
  unsigned short* Wt1 = (unsigned short*)(base + off); off = align_up(off + (size_t)NEXP * HSZ * FFND * 2, 1 << 20);
  unsigned short* Wt2 = (unsigned short*)(base + off); off += (size_t)NEXP * FFND * HSZ * 2;
  (void)ws_size;

  hipMemsetAsync(d_out, 0, (size_t)out_size * sizeof(float), stream);

  k_route <<<1, 1024, 0, stream>>>(ei, ew, counts, offsets, rowT, rowC);
  k_gather<<<NSLOT, 256, 0, stream>>>(x, rowT, Xg);

  // merged weight transform: z<8 -> w1 [HSZ][FFND]->Wt1; z>=8 -> w2 -> Wt2
  k_transpose2<<<dim3(1024, 2 * NEXP), 256, 0, stream>>>(w1, w2, Wt1, Wt2);

  // worst case one expert owns all 8192 rows -> 64 m-blocks; extras early-exit
  k_gemm1<<<dim3(FFND / BN, 64, NEXP), 256, 0, stream>>>(Xg, Wt1, H, counts, offsets);
  // y = mblk*KSPLIT + ks : 1024 working blocks to fill 3 blocks/CU residency
  k_gemm2<<<dim3(HSZ / BN, 64 * KSPLIT, NEXP), 256, 0, stream>>>(H, Wt2, out, counts, offsets, rowT, rowC);
}

// Round 8
// 565.524 us; speedup vs baseline: 1.0998x; 1.0204x over previous
//
#include <hip/hip_runtime.h>
#include <stdint.h>

#define SLEN 2048
#define BSZ  2
#define HSZ  1024
#define FFND 4096
#define NEXP 8
#define TOPK 2
#define NTOK (SLEN*BSZ)        // 4096
#define NSLOT (NTOK*TOPK)      // 8192

#define BM 128
#define BN 128
#define BK 32
#define STAGE (BM * BK)        // 4096 shorts per operand per stage
#define RING 3                 // LDS ring depth: prefetch distance 2 K-tiles

#define KSPLIT 2
#define HALFK (FFND / KSPLIT)  // 2048

// flattened grids (both % 8 == 0 -> bijective XCD swizzle)
#define NWG1 (32 * 64 * NEXP)          // 16384; chunk 2048 = one expert
#define NWG2 (8 * 64 * KSPLIT * NEXP)  // 8192;  chunk 1024 = one expert

using short8 = __attribute__((ext_vector_type(8))) short;
using f32x4  = __attribute__((ext_vector_type(4))) float;

typedef __attribute__((address_space(1))) const unsigned int gu32;
typedef __attribute__((address_space(3))) unsigned int lu32;

__device__ inline void async_copy16(const void* g, void* l){
  // DMA 16B/lane global->LDS; LDS dest = wave-uniform base + lane*16
  __builtin_amdgcn_global_load_lds((gu32*)g, (lu32*)l, 16, 0, 0);
}

__device__ inline unsigned short f2bf(float f){
  unsigned u = __builtin_bit_cast(unsigned, f);
  u += 0x7FFFu + ((u >> 16) & 1u);      // round-to-nearest-even
  return (unsigned short)(u >> 16);
}

__device__ inline float gelu_tanh(float x){
  // jax.nn.gelu default (approximate=True)
  float u = 0.7978845608028654f * (x + 0.044715f * x * x * x);
  return 0.5f * x * (1.0f + tanhf(u));
}

// ---------------- fused routing: count + scan + assign (one block) ----------
__global__ __launch_bounds__(1024) void k_route(const int* __restrict__ ei,
                                                const float* __restrict__ ew,
                                                int* __restrict__ counts,
                                                int* __restrict__ offsets,
                                                int* __restrict__ rowT,
                                                float* __restrict__ rowC){
  __shared__ int hist[NEXP];
  __shared__ int fill[NEXP];
  const int tid = threadIdx.x;
  if (tid < NEXP) hist[tid] = 0;
  __syncthreads();
  int myE[NSLOT / 1024];
  #pragma unroll
  for (int p = 0; p < NSLOT / 1024; p++){
    myE[p] = ei[tid + p * 1024];
    atomicAdd(&hist[myE[p]], 1);
  }
  __syncthreads();
  if (tid == 0){
    int acc = 0;
    for (int e = 0; e < NEXP; e++){
      offsets[e] = acc; counts[e] = hist[e]; fill[e] = acc; acc += hist[e];
    }
  }
  __syncthreads();
  #pragma unroll
  for (int p = 0; p < NSLOT / 1024; p++){
    int i = tid + p * 1024;
    int slot = atomicAdd(&fill[myE[p]], 1);
    rowT[slot] = i >> 1;       // token index (i = t*TOPK + k)
    rowC[slot] = ew[i];
  }
}

__global__ void k_gather(const float* __restrict__ x, const int* __restrict__ rowT,
                         unsigned short* __restrict__ Xg){
  int slot = blockIdx.x;
  int t = rowT[slot];
  int c = threadIdx.x * 4;
  float4 v = *(const float4*)(x + (size_t)t * HSZ + c);
  ushort4 o;
  o.x = f2bf(v.x); o.y = f2bf(v.y); o.z = f2bf(v.z); o.w = f2bf(v.w);
  *(ushort4*)(Xg + (size_t)slot * HSZ + c) = o;
}

// ------- merged weight transform: fp32 [R][C] -> bf16 [C][R], w1 & w2 -------
__global__ __launch_bounds__(256) void k_transpose2(const float* __restrict__ w1,
                                                    const float* __restrict__ w2,
                                                    unsigned short* __restrict__ Wt1,
                                                    unsigned short* __restrict__ Wt2){
  __shared__ unsigned short tile[64][65];
  const int tid = threadIdx.x;
  int z = blockIdx.y;
  const float* src; unsigned short* dst; int R, C, r0, c0;
  if (z < NEXP){
    src = w1 + (size_t)z * HSZ * FFND; dst = Wt1 + (size_t)z * HSZ * FFND;
    R = HSZ; C = FFND;
    c0 = (blockIdx.x & 63) * 64; r0 = (blockIdx.x >> 6) * 64;
  } else {
    z -= NEXP;
    src = w2 + (size_t)z * FFND * HSZ; dst = Wt2 + (size_t)z * FFND * HSZ;
    R = FFND; C = HSZ;
    c0 = (blockIdx.x & 15) * 64; r0 = (blockIdx.x >> 4) * 64;
  }
  #pragma unroll
  for (int p = 0; p < 4; p++){
    int r  = p * 16 + (tid >> 4);
    int cc = (tid & 15) * 4;
    float4 v = *(const float4*)(src + (size_t)(r0 + r) * C + c0 + cc);
    tile[r][cc]   = f2bf(v.x);
    tile[r][cc+1] = f2bf(v.y);
    tile[r][cc+2] = f2bf(v.z);
    tile[r][cc+3] = f2bf(v.w);
  }
  __syncthreads();
  #pragma unroll
  for (int p = 0; p < 4; p++){
    int c  = p * 16 + (tid >> 4);
    int rr = (tid & 15) * 4;
    ushort4 o;
    o.x = tile[rr][c]; o.y = tile[rr+1][c]; o.z = tile[rr+2][c]; o.w = tile[rr+3][c];
    *(ushort4*)(dst + (size_t)(c0 + c) * R + r0 + rr) = o;
  }
}

// -------- GEMM core: ring-3 LDS, distance-2 prefetch, counted vmcnt --------
// (R7-proven: 577us total). See R7 comments; unchanged this round.
__device__ inline void gemm_core(const unsigned short* __restrict__ Ag, int lda, int rows,
                                 const unsigned short* __restrict__ Bg, int ldb, int K,
                                 unsigned short* As, unsigned short* Bs,
                                 f32x4 acc[4][4])
{
  const int tid  = threadIdx.x;
  const int lane = tid & 63;
  const int wid  = tid >> 6;
  const int wm   = (wid & 1) * 64;
  const int wn   = (wid >> 1) * 64;
  const int q    = lane >> 4;
  const int l16  = lane & 15;

  // chunk ids (16B each) owned by this lane
  const int c0 = (wid * 2) * 64 + lane;
  const int c1 = c0 + 64;
  // per-lane 32-bit byte offsets over uniform bases
  unsigned aoff0 = (unsigned)(min(c0 >> 2, rows - 1) * lda + (c0 & 3) * 8) * 2u;
  unsigned aoff1 = (unsigned)(min(c1 >> 2, rows - 1) * lda + (c1 & 3) * 8) * 2u;
  unsigned boff0 = (unsigned)((c0 >> 2) * ldb + (c0 & 3) * 8) * 2u;
  unsigned boff1 = (unsigned)((c1 >> 2) * ldb + (c1 & 3) * 8) * 2u;
  const char* A8 = (const char*)Ag;
  const char* B8 = (const char*)Bg;
  unsigned short* al0 = As + (wid * 2) * 512;
  unsigned short* bl0 = Bs + (wid * 2) * 512;

  auto stage = [&](int s){
    async_copy16(A8 + aoff0, al0 + s * STAGE);
    async_copy16(B8 + boff0, bl0 + s * STAGE);
    async_copy16(A8 + aoff1, al0 + s * STAGE + 512);
    async_copy16(B8 + boff1, bl0 + s * STAGE + 512);
  };
  auto advance = [&](){ aoff0 += BK * 2; aoff1 += BK * 2; boff0 += BK * 2; boff1 += BK * 2; };

  const int niter = K / BK;
  stage(0); advance();
  stage(1); advance();              // offsets now point at tile 2

  int rd = 0, wr2 = 2;              // ring slots: read tile k, write tile k+2
  for (int k = 0; k < niter; k++){
    // tile k guaranteed complete; k+1,k+2 may stay in flight (counted, T4)
    asm volatile("s_waitcnt vmcnt(4)" ::: "memory");
    __builtin_amdgcn_s_barrier();
    asm volatile("" ::: "memory");

    stage(wr2);                     // tile k+2 (or clamped dead re-read at tail)
    if (k + 3 < niter) advance();

    const unsigned short* Ak = As + rd * STAGE;
    const unsigned short* Bk = Bs + rd * STAGE;
    short8 af[4], bfr[4];
    #pragma unroll
    for (int i = 0; i < 4; i++)
      af[i] = *(const short8*)(Ak + (wm + i * 16 + l16) * BK + q * 8);
    #pragma unroll
    for (int j = 0; j < 4; j++)
      bfr[j] = *(const short8*)(Bk + (wn + j * 16 + l16) * BK + q * 8);

    __builtin_amdgcn_s_setprio(1);
    #pragma unroll
    for (int i = 0; i < 4; i++)
      #pragma unroll
      for (int j = 0; j < 4; j++)
        acc[i][j] = __builtin_amdgcn_mfma_f32_16x16x32_bf16(af[i], bfr[j], acc[i][j], 0, 0, 0);
    __builtin_amdgcn_s_setprio(0);

    rd  = (rd  + 1 == RING) ? 0 : rd  + 1;
    wr2 = (wr2 + 1 == RING) ? 0 : wr2 + 1;
  }
  // drain dead-slot prefetches before LDS reuse / exit
  asm volatile("s_waitcnt vmcnt(0)" ::: "memory");
  __builtin_amdgcn_s_barrier();
  asm volatile("" ::: "memory");
}

// ---------------- GEMM1: H = gelu(Xg @ Wt1[e]^T), 128x128 tile --------------
// 1D grid + bijective XCD swizzle (T1): chunk c = expert c; within chunk
// x-fastest so the 32 n-blocks sharing an Xg A-panel run on ONE XCD's L2.
__global__ __launch_bounds__(256, 4) void k_gemm1(const unsigned short* __restrict__ Xg,
                                                  const unsigned short* __restrict__ Wt1,
                                                  unsigned short* __restrict__ H,
                                                  const int* __restrict__ counts,
                                                  const int* __restrict__ offsets)
{
  __shared__ unsigned short smem[2 * RING * STAGE];   // 48 KB -> 3 blocks/CU
  unsigned short* As = smem;
  unsigned short* Bs = smem + RING * STAGE;
  const int bid  = blockIdx.x;
  const int swz  = (bid & 7) * (NWG1 / 8) + (bid >> 3);
  const int nblk = swz & 31;              // x fastest: 32 n-blocks
  const int rem  = swz >> 5;
  const int mblk = rem & 63;
  const int e    = rem >> 6;
  const int cnt  = counts[e];
  if (mblk * BM >= cnt) return;
  const int n0   = nblk * BN;
  const int row0 = offsets[e] + mblk * BM;
  const int rows = min(BM, cnt - mblk * BM);

  f32x4 acc[4][4] = {};
  gemm_core(Xg + (size_t)row0 * HSZ, HSZ, rows,
            Wt1 + (size_t)e * HSZ * FFND + (size_t)n0 * HSZ, HSZ, HSZ, As, Bs, acc);
  __syncthreads();   // full drain before reusing smem as scratch

  const int lane = threadIdx.x & 63, wid = threadIdx.x >> 6;
  const int wm = (wid & 1) * 64, wn = (wid >> 1) * 64;
  const int q = lane >> 4, l16 = lane & 15;

  // per-wave LDS repack: 16x64 bf16 subtile (stride 68), b128 readback,
  // dwordx4 global stores. Scratch is wave-private.
  unsigned short* scr = smem + wid * (16 * 68);
  #pragma unroll
  for (int i = 0; i < 4; i++){
    #pragma unroll
    for (int j = 0; j < 4; j++)
      #pragma unroll
      for (int r = 0; r < 4; r++)
        scr[(q * 4 + r) * 68 + j * 16 + l16] = f2bf(gelu_tanh(acc[i][j][r]));
    #pragma unroll
    for (int p = 0; p < 2; p++){
      int rr = p * 8 + (lane >> 3);
      int cc = (lane & 7) * 8;
      short8 v = *(const short8*)(scr + rr * 68 + cc);
      int grow = wm + i * 16 + rr;
      if (grow < rows)
        *(short8*)(H + (size_t)(row0 + grow) * FFND + n0 + wn + cc) = v;
    }
  }
}

// ------- GEMM2: out[t] += coef * (H @ Wt2[e]^T), 128x128 tile, K-split ------
// 1D grid + XCD swizzle: chunk c = expert c. Decode ks-major so one K-half of
// Wt2[e] (4 MB) stays L2-resident for all its m-blocks before switching half.
__global__ __launch_bounds__(256, 4) void k_gemm2(const unsigned short* __restrict__ H,
                                                  const unsigned short* __restrict__ Wt2,
                                                  float* __restrict__ out,
                                                  const int* __restrict__ counts,
                                                  const int* __restrict__ offsets,
                                                  const int* __restrict__ rowT,
                                                  const float* __restrict__ rowC)
{
  __shared__ unsigned short smem[2 * RING * STAGE];   // 48 KB
  unsigned short* As = smem;
  unsigned short* Bs = smem + RING * STAGE;
  const int bid  = blockIdx.x;
  const int swz  = (bid & 7) * (NWG2 / 8) + (bid >> 3);
  const int nblk = swz & 7;               // x fastest: 8 n-blocks
  const int rem  = swz >> 3;
  const int y    = rem & 127;
  const int e    = rem >> 7;
  const int ks   = y >> 6;                // ks-major: all mblks of half 0 first
  const int mblk = y & 63;
  const int cnt  = counts[e];
  if (mblk * BM >= cnt) return;
  const int n0   = nblk * BN;
  const int row0 = offsets[e] + mblk * BM;
  const int rows = min(BM, cnt - mblk * BM);

  f32x4 acc[4][4] = {};
  gemm_core(H + (size_t)row0 * FFND + ks * HALFK, FFND, rows,
            Wt2 + (size_t)e * FFND * HSZ + (size_t)n0 * FFND + ks * HALFK, FFND,
            HALFK, As, Bs, acc);

  const int lane = threadIdx.x & 63, wid = threadIdx.x >> 6;
  const int wm = (wid & 1) * 64, wn = (wid >> 1) * 64;
  const int q = lane >> 4, l16 = lane & 15;
  #pragma unroll
  for (int i = 0; i < 4; i++)
    #pragma unroll
    for (int r = 0; r < 4; r++){
      int row = wm + i * 16 + q * 4 + r;
      if (row < rows){
        int g = row0 + row;
        float cf = rowC[g];
        float* op = out + (size_t)rowT[g] * HSZ + n0 + wn;
        #pragma unroll
        for (int j = 0; j < 4; j++)
          atomicAdd(op + j * 16 + l16, cf * acc[i][j][r]);
      }
    }
}

// ---------------- launch ----------------
static inline size_t align_up(size_t v, size_t a){ return (v + a - 1) & ~(a - 1); }

extern "C" void kernel_launch(void* const* d_in, const int* in_sizes, int n_in,
                              void* d_out, int out_size, void* d_ws, size_t ws_size,
                              hipStream_t stream) {
  const float* x  = (const float*)d_in[0];
  const float* ew = (const float*)d_in[1];
  const int*   ei = (const int*)d_in[2];
  const float* w1 = (const float*)d_in[3];
  const float* w2 = (const float*)d_in[4];
  float* out = (float*)d_out;

  // workspace layout (bytes)
  char* base = (char*)d_ws;
  size_t off = 0;
  int* counts  = (int*)(base + off); off += 64;
  int* offsets = (int*)(base + off); off = align_up(off + 64, 4096);
  int* rowT    = (int*)(base + off); off += (size_t)NSLOT * 4;
  float* rowC  = (float*)(base + off); off = align_up(off + (size_t)NSLOT * 4, 1 << 20);
  unsigned short* Xg  = (unsigned short*)(base + off); off = align_up(off + (size_t)NSLOT * HSZ * 2, 1 << 20);
  unsigned short* H   = (unsigned short*)(base + off); off = align_up(off + (size_t)NSLOT * FFND * 2, 1 << 20);
  unsigned short* Wt1 = (unsigned short*)(base + off); off = align_up(off + (size_t)NEXP * HSZ * FFND * 2, 1 << 20);
  unsigned short* Wt2 = (unsigned short*)(base + off); off += (size_t)NEXP * FFND * HSZ * 2;
  (void)ws_size;

  hipMemsetAsync(d_out, 0, (size_t)out_size * sizeof(float), stream);

  k_route <<<1, 1024, 0, stream>>>(ei, ew, counts, offsets, rowT, rowC);
  k_gather<<<NSLOT, 256, 0, stream>>>(x, rowT, Xg);

  // merged weight transform: z<8 -> w1 [HSZ][FFND]->Wt1; z>=8 -> w2 -> Wt2
  k_transpose2<<<dim3(1024, 2 * NEXP), 256, 0, stream>>>(w1, w2, Wt1, Wt2);

  // flattened 1D grids with XCD chunk swizzle (T1); dead blocks early-exit
  k_gemm1<<<NWG1, 256, 0, stream>>>(Xg, Wt1, H, counts, offsets);
  k_gemm2<<<NWG2, 256, 0, stream>>>(H, Wt2, out, counts, offsets, rowT, rowC);
}